// Round 17
// baseline (45.000 us; speedup 1.0000x reference)
//
#include <hip/hip_runtime.h>
#include <hip/hip_cooperative_groups.h>

namespace cg = cooperative_groups;

constexpr int T_DIM       = 16;
constexpr int TOK         = 16384;
constexpr int E_DIM       = 128;
constexpr int N_NODE_C    = 8192;
constexpr int NUM_NODES_C = 50000;
constexpr int COMP_LEN_C  = 64;
constexpr int MAX_LEN_C   = 782;
constexpr int COMP_DIM_C  = 32;
constexpr float EPS_F     = 1e-5f;

constexpr int D2      = COMP_LEN_C * COMP_DIM_C;   // 2048
constexpr int GRID_C  = 1024;                      // 16 t x 64 chunks, 4/CU
constexpr int BLK_C   = 256;                       // 4 waves
constexpr int PER_T   = 64;
constexpr int RPB     = 128;                       // rows per block

// d_ws: W8 (3.2MB) | Agg (128KB). One memset zeroes both (replay-safe).
constexpr size_t W8_BYTES   = (size_t)NUM_NODES_C * COMP_LEN_C;   // 3,200,000
constexpr size_t AGG_OFF    = 3211264;                            // 4KB-aligned
constexpr size_t AGG_BYTES  = (size_t)T_DIM * D2 * sizeof(float); // 131,072
constexpr size_t ZERO_BYTES = AGG_OFF + AGG_BYTES;

struct SharedT {
  float    vtile[RPB][COMP_DIM_C];  // 16KB
  unsigned atile[RPB][16];          // 8KB
  float    red[16];
};

// ---- Phase A: dense x-stream + LN + pool -> vtile; prefetch node ids.
__device__ __forceinline__ void phaseA_stream(
    SharedT& sh, int t, int chunk, const float* __restrict__ x,
    const float* __restrict__ g1, const float* __restrict__ b1,
    const int* __restrict__ node_idx, int* nid8) {
  const int tid = threadIdx.x, lane = tid & 63, wave = tid >> 6;
  const int g = lane & 31, half = lane >> 5;
  const int rbase = chunk * RPB;
  const int* nit = node_idx + (size_t)t * N_NODE_C;
  const float4* xv = reinterpret_cast<const float4*>(x + (size_t)t * TOK * E_DIM);

#pragma unroll
  for (int j = 0; j < 8; ++j) nid8[j] = nit[rbase + ((tid + j * 256) >> 4)];

  const float4 gv = *reinterpret_cast<const float4*>(g1 + g * 4);
  const float4 bv = *reinterpret_cast<const float4*>(b1 + g * 4);
  const float sg = gv.x + gv.y + gv.z + gv.w;
  const float sb = bv.x + bv.y + bv.z + bv.w;
  const int wr0 = rbase + wave * 32;

  float4 xd[8];
#pragma unroll
  for (int i = 0; i < 8; ++i)
    xd[i] = xv[(size_t)(wr0 + 2 * i) * 32 + lane];
#pragma unroll
  for (int i = 0; i < 8; ++i) {
    const float4 a = xd[i];
    float s = (a.x + a.y) + (a.z + a.w);
    float q = a.x * a.x + a.y * a.y + a.z * a.z + a.w * a.w;
#pragma unroll
    for (int m = 1; m < 32; m <<= 1) { s += __shfl_xor(s, m); q += __shfl_xor(q, m); }
    float mu = s * (1.0f / E_DIM);
    float rstd = rsqrtf(q * (1.0f / E_DIM) - mu * mu + EPS_F);
    float dxg = a.x * gv.x + a.y * gv.y + a.z * gv.z + a.w * gv.w;
    sh.vtile[wave * 32 + 2 * i + half][g] = (dxg - mu * sg) * rstd + sb;
  }
#pragma unroll
  for (int i = 0; i < 8; ++i)
    xd[i] = xv[(size_t)(wr0 + 16 + 2 * i) * 32 + lane];
#pragma unroll
  for (int i = 0; i < 8; ++i) {
    const float4 a = xd[i];
    float s = (a.x + a.y) + (a.z + a.w);
    float q = a.x * a.x + a.y * a.y + a.z * a.z + a.w * a.w;
#pragma unroll
    for (int m = 1; m < 32; m <<= 1) { s += __shfl_xor(s, m); q += __shfl_xor(q, m); }
    float mu = s * (1.0f / E_DIM);
    float rstd = rsqrtf(q * (1.0f / E_DIM) - mu * mu + EPS_F);
    float dxg = a.x * gv.x + a.y * gv.y + a.z * gv.z + a.w * gv.w;
    sh.vtile[wave * 32 + 16 + 2 * i + half][g] = (dxg - mu * sg) * rstd + sb;
  }
}

// ---- Phase B: W-gather -> atile; branch-free u8 GEMM; atomic flush into Agg.
__device__ __forceinline__ void phaseB_gemmflush(
    SharedT& sh, int t, const unsigned* __restrict__ W32, const int* nid8,
    float* __restrict__ Agg) {
  const int tid = threadIdx.x;
  __syncthreads();   // vtile (and in fallback: dispatch-ordered W) ready

  unsigned wg8[8];
#pragma unroll
  for (int j = 0; j < 8; ++j)
    wg8[j] = W32[(size_t)nid8[j] * 16 + ((tid + j * 256) & 15)];
#pragma unroll
  for (int j = 0; j < 8; ++j) {
    int w = tid + j * 256;
    sh.atile[w >> 4][w & 15] = wg8[j];
  }
  __syncthreads();

  const int c4 = tid >> 4, d2 = tid & 15;
  float2 acc0{0,0}, acc1{0,0}, acc2{0,0}, acc3{0,0};
  const float2* vt2 = reinterpret_cast<const float2*>(&sh.vtile[0][0]);
#pragma unroll 4
  for (int k = 0; k < RPB; ++k) {
    unsigned a4 = sh.atile[k][c4];
    float2 v2 = vt2[k * 16 + d2];
    float a0 = (float)(a4 & 255u),         a1 = (float)((a4 >> 8) & 255u);
    float a2 = (float)((a4 >> 16) & 255u), a3 = (float)((a4 >> 24) & 255u);
    acc0.x += a0 * v2.x; acc0.y += a0 * v2.y;
    acc1.x += a1 * v2.x; acc1.y += a1 * v2.y;
    acc2.x += a2 * v2.x; acc2.y += a2 * v2.y;
    acc3.x += a3 * v2.x; acc3.y += a3 * v2.y;
  }
  float* aggt = Agg + (size_t)t * D2;
  const int b0 = c4 * 4;
  atomicAdd(&aggt[(b0 + 0) * 32 + d2 * 2],     acc0.x);
  atomicAdd(&aggt[(b0 + 0) * 32 + d2 * 2 + 1], acc0.y);
  atomicAdd(&aggt[(b0 + 1) * 32 + d2 * 2],     acc1.x);
  atomicAdd(&aggt[(b0 + 1) * 32 + d2 * 2 + 1], acc1.y);
  atomicAdd(&aggt[(b0 + 2) * 32 + d2 * 2],     acc2.x);
  atomicAdd(&aggt[(b0 + 2) * 32 + d2 * 2 + 1], acc2.y);
  atomicAdd(&aggt[(b0 + 3) * 32 + d2 * 2],     acc3.x);
  atomicAdd(&aggt[(b0 + 3) * 32 + d2 * 2 + 1], acc3.y);
}

// ---- Phase C: final LN2 per t (reads 128KB Agg).
__device__ __forceinline__ void phaseC_final(
    SharedT& sh, int t, const float* __restrict__ Agg, const float* __restrict__ g2,
    const float* __restrict__ b2, float* __restrict__ out) {
  const float scale = 1.0f / (4.0f * (float)MAX_LEN_C);
  const int tid = threadIdx.x;
  float y[8]; float s = 0.f, q = 0.f;
#pragma unroll
  for (int k = 0; k < 8; ++k) {
    float v = Agg[(size_t)t * D2 + tid * 8 + k] * scale;
    y[k] = v; s += v; q += v * v;
  }
#pragma unroll
  for (int m = 1; m < 64; m <<= 1) { s += __shfl_xor(s, m); q += __shfl_xor(q, m); }
  const int w = tid >> 6, ln = tid & 63;
  if (ln == 0) { sh.red[w] = s; sh.red[8 + w] = q; }
  __syncthreads();
  float ts = sh.red[0] + sh.red[1] + sh.red[2] + sh.red[3];
  float tq = sh.red[8] + sh.red[9] + sh.red[10] + sh.red[11];
  float mu = ts * (1.0f / D2);
  float rstd = rsqrtf(tq * (1.0f / D2) - mu * mu + EPS_F);
#pragma unroll
  for (int k = 0; k < 8; ++k) {
    int idx = tid * 8 + k;
    out[(size_t)t * D2 + idx] = (y[k] - mu) * rstd * g2[idx] + b2[idx];
  }
}

// ---- Coop mega: {build ∥ stream} -> sync -> {gather+GEMM+flush} -> sync -> final.
// W8 and Agg are pre-zeroed by hipMemsetAsync before this kernel.
__global__ __launch_bounds__(256, 4) void mega_kernel(
    const float* __restrict__ x, const float* __restrict__ g1, const float* __restrict__ b1,
    const int* __restrict__ node_idx, const int* __restrict__ sidx,
    const float* __restrict__ g2, const float* __restrict__ b2,
    unsigned* __restrict__ W8w, float* __restrict__ Agg, float* __restrict__ out) {
  cg::grid_group grid = cg::this_grid();
  __shared__ SharedT sh;
  const int gtid = blockIdx.x * BLK_C + threadIdx.x;
  const int t = blockIdx.x >> 6, chunk = blockIdx.x & 63;

  // Build-W (first 196 blocks) overlaps every block's x-stream.
  if (gtid < COMP_LEN_C * MAX_LEN_C) {
    int c = gtid / MAX_LEN_C;
    int n = sidx[gtid];
    int byteoff = n * COMP_LEN_C + c;
    atomicAdd(&W8w[byteoff >> 2], 1u << (8 * (byteoff & 3)));
  }
  int nid8[8];
  phaseA_stream(sh, t, chunk, x, g1, b1, node_idx, nid8);
  grid.sync();                       // W built; vtile resident in LDS
  phaseB_gemmflush(sh, t, (const unsigned*)W8w, nid8, Agg);
  grid.sync();                       // Agg complete
  if (blockIdx.x < T_DIM) phaseC_final(sh, blockIdx.x, Agg, g2, b2, out);
}

// ---- Fallback (non-coop), identical math, dispatch-ordered.
__global__ void build_w8_kernel(const int* __restrict__ sidx, unsigned* __restrict__ W8w) {
  const int c  = blockIdx.x >> 2;
  const int jc = blockIdx.x & 3;
  const int j  = jc * 196 + threadIdx.x;
  if (j < MAX_LEN_C && threadIdx.x < 196) {
    int n = sidx[c * MAX_LEN_C + j];
    int byteoff = n * COMP_LEN_C + c;
    atomicAdd(&W8w[byteoff >> 2], 1u << (8 * (byteoff & 3)));
  }
}
__global__ __launch_bounds__(256, 4) void main_nc(
    const float* __restrict__ x, const float* __restrict__ g1, const float* __restrict__ b1,
    const int* __restrict__ node_idx, const unsigned* __restrict__ W32,
    float* __restrict__ Agg) {
  __shared__ SharedT sh;
  const int t = blockIdx.x >> 6, chunk = blockIdx.x & 63;
  int nid8[8];
  phaseA_stream(sh, t, chunk, x, g1, b1, node_idx, nid8);
  phaseB_gemmflush(sh, t, W32, nid8, Agg);
}
__global__ __launch_bounds__(256) void final_nc(
    const float* __restrict__ Agg, const float* __restrict__ g2,
    const float* __restrict__ b2, float* __restrict__ out) {
  __shared__ SharedT sh;
  phaseC_final(sh, blockIdx.x, Agg, g2, b2, out);
}

extern "C" void kernel_launch(void* const* d_in, const int* in_sizes, int n_in,
                              void* d_out, int out_size, void* d_ws, size_t ws_size,
                              hipStream_t stream) {
  const float* x     = (const float*)d_in[0];
  const float* ln1_g = (const float*)d_in[1];
  const float* ln1_b = (const float*)d_in[2];
  const float* ln2_g = (const float*)d_in[3];
  const float* ln2_b = (const float*)d_in[4];
  const int* node_idx = (const int*)d_in[5];
  const int* sidx     = (const int*)d_in[6];
  float* out = (float*)d_out;

  unsigned char* ws = (unsigned char*)d_ws;
  unsigned* W8w = (unsigned*)ws;
  float* Agg = (float*)(ws + AGG_OFF);

  hipMemsetAsync(ws, 0, ZERO_BYTES, stream);   // W8 + Agg (replay-safe)

  int maxActive = 0;
  hipError_t occ = hipOccupancyMaxActiveBlocksPerMultiprocessor(
      &maxActive, (const void*)mega_kernel, BLK_C, 0);
  bool coop = (occ == hipSuccess) && (maxActive >= 4);   // 1024 blocks / 256 CU

  if (coop) {
    void* args[] = {(void*)&x, (void*)&ln1_g, (void*)&ln1_b, (void*)&node_idx,
                    (void*)&sidx, (void*)&ln2_g, (void*)&ln2_b,
                    (void*)&W8w, (void*)&Agg, (void*)&out};
    hipError_t e = hipLaunchCooperativeKernel((void*)mega_kernel, dim3(GRID_C),
                                              dim3(BLK_C), args, 0, stream);
    if (e == hipSuccess) return;
  }

  build_w8_kernel<<<COMP_LEN_C * 4, 256, 0, stream>>>(sidx, W8w);
  main_nc<<<GRID_C, BLK_C, 0, stream>>>(x, ln1_g, ln1_b, node_idx,
                                        (const unsigned*)W8w, Agg);
  final_nc<<<T_DIM, 256, 0, stream>>>(Agg, ln2_g, ln2_b, out);
}

// Round 18
// 42.307 us; speedup vs baseline: 1.0637x; 1.0637x over previous
//
#include <hip/hip_runtime.h>
#include <hip/hip_cooperative_groups.h>

namespace cg = cooperative_groups;

constexpr int T_DIM       = 16;
constexpr int TOK         = 16384;
constexpr int E_DIM       = 128;
constexpr int N_NODE_C    = 8192;
constexpr int NUM_NODES_C = 50000;
constexpr int COMP_LEN_C  = 64;
constexpr int MAX_LEN_C   = 782;
constexpr int COMP_DIM_C  = 32;
constexpr float EPS_F     = 1e-5f;

constexpr int D2      = COMP_LEN_C * COMP_DIM_C;   // 2048
constexpr int GRID_C  = 1024;                      // 16 t x 64 chunks; 4 blocks/CU
constexpr int BLK_C   = 512;                       // 8 waves -> 8 waves/SIMD resident
constexpr int PER_T   = 64;
constexpr int RPB     = 128;                       // rows per block

// d_ws: W8 (3.2MB) | Agg (128KB). One memset zeroes both (replay-safe).
constexpr size_t W8_BYTES   = (size_t)NUM_NODES_C * COMP_LEN_C;   // 3,200,000
constexpr size_t AGG_OFF    = 3211264;                            // 4KB-aligned
constexpr size_t AGG_BYTES  = (size_t)T_DIM * D2 * sizeof(float); // 131,072
constexpr size_t ZERO_BYTES = AGG_OFF + AGG_BYTES;

struct SharedT {
  float    vtile[RPB][COMP_DIM_C];  // 16KB
  unsigned atile[RPB][16];          // 8KB
  float    red[16];
};

// ---- Phase A: dense x-stream + LN + pool -> vtile; prefetch node ids.
// 8 waves x 16 rows each; per iter a wave covers 2 rows (32 lanes/row).
__device__ __forceinline__ void phaseA_stream(
    SharedT& sh, int t, int chunk, const float* __restrict__ x,
    const float* __restrict__ g1, const float* __restrict__ b1,
    const int* __restrict__ node_idx, int* nid4) {
  const int tid = threadIdx.x, lane = tid & 63, wave = tid >> 6;
  const int g = lane & 31, half = lane >> 5;
  const int rbase = chunk * RPB;
  const int* nit = node_idx + (size_t)t * N_NODE_C;
  const float4* xv = reinterpret_cast<const float4*>(x + (size_t)t * TOK * E_DIM);

  // 2048 atile words / 512 threads = 4 each; nid broadcast loads first.
#pragma unroll
  for (int j = 0; j < 4; ++j) nid4[j] = nit[rbase + ((tid + j * 512) >> 4)];

  const float4 gv = *reinterpret_cast<const float4*>(g1 + g * 4);
  const float4 bv = *reinterpret_cast<const float4*>(b1 + g * 4);
  const float sg = gv.x + gv.y + gv.z + gv.w;
  const float sb = bv.x + bv.y + bv.z + bv.w;
  const int wr0 = rbase + wave * 16;

  float4 xd[8];
#pragma unroll
  for (int i = 0; i < 8; ++i)
    xd[i] = xv[(size_t)(wr0 + 2 * i) * 32 + lane];   // 1KB dense per wave-load
#pragma unroll
  for (int i = 0; i < 8; ++i) {
    const float4 a = xd[i];
    float s = (a.x + a.y) + (a.z + a.w);
    float q = a.x * a.x + a.y * a.y + a.z * a.z + a.w * a.w;
#pragma unroll
    for (int m = 1; m < 32; m <<= 1) { s += __shfl_xor(s, m); q += __shfl_xor(q, m); }
    float mu = s * (1.0f / E_DIM);
    float rstd = rsqrtf(q * (1.0f / E_DIM) - mu * mu + EPS_F);
    float dxg = a.x * gv.x + a.y * gv.y + a.z * gv.z + a.w * gv.w;
    sh.vtile[wave * 16 + 2 * i + half][g] = (dxg - mu * sg) * rstd + sb;
  }
}

// ---- Phase B: W-gather -> atile; branch-free u8 GEMM (2c x 2d per thread);
// atomic flush into Agg.
__device__ __forceinline__ void phaseB_gemmflush(
    SharedT& sh, int t, const unsigned* __restrict__ W32, const int* nid4,
    float* __restrict__ Agg) {
  const int tid = threadIdx.x;
  __syncthreads();   // vtile ready (coop: W ordered by grid.sync before this)

  unsigned wg4[4];
#pragma unroll
  for (int j = 0; j < 4; ++j)
    wg4[j] = W32[(size_t)nid4[j] * 16 + ((tid + j * 512) & 15)];
#pragma unroll
  for (int j = 0; j < 4; ++j) {
    int w = tid + j * 512;
    sh.atile[w >> 4][w & 15] = wg4[j];
  }
  __syncthreads();

  // thread -> c pair (c2*2, c2*2+1) x d pair (d2*2, d2*2+1)
  const int c2 = tid >> 4, d2 = tid & 15;
  const int aw = c2 >> 1, ash = (c2 & 1) * 16;     // atile word, byte shift base
  float2 acc0{0,0}, acc1{0,0};
  const float2* vt2 = reinterpret_cast<const float2*>(&sh.vtile[0][0]);
#pragma unroll 4
  for (int k = 0; k < RPB; ++k) {
    unsigned a4 = sh.atile[k][aw];
    float2 v2 = vt2[k * 16 + d2];
    float a0 = (float)((a4 >> ash) & 255u);
    float a1 = (float)((a4 >> (ash + 8)) & 255u);
    acc0.x += a0 * v2.x; acc0.y += a0 * v2.y;
    acc1.x += a1 * v2.x; acc1.y += a1 * v2.y;
  }
  float* aggt = Agg + (size_t)t * D2;
  const int c0 = c2 * 2;
  atomicAdd(&aggt[(c0 + 0) * 32 + d2 * 2],     acc0.x);
  atomicAdd(&aggt[(c0 + 0) * 32 + d2 * 2 + 1], acc0.y);
  atomicAdd(&aggt[(c0 + 1) * 32 + d2 * 2],     acc1.x);
  atomicAdd(&aggt[(c0 + 1) * 32 + d2 * 2 + 1], acc1.y);
}

// ---- Phase C: final LN2 per t (512 threads x 4 elems).
__device__ __forceinline__ void phaseC_final(
    SharedT& sh, int t, const float* __restrict__ Agg, const float* __restrict__ g2,
    const float* __restrict__ b2, float* __restrict__ out) {
  const float scale = 1.0f / (4.0f * (float)MAX_LEN_C);
  const int tid = threadIdx.x;
  float y[4]; float s = 0.f, q = 0.f;
#pragma unroll
  for (int k = 0; k < 4; ++k) {
    float v = Agg[(size_t)t * D2 + tid * 4 + k] * scale;
    y[k] = v; s += v; q += v * v;
  }
#pragma unroll
  for (int m = 1; m < 64; m <<= 1) { s += __shfl_xor(s, m); q += __shfl_xor(q, m); }
  const int w = tid >> 6, ln = tid & 63;
  if (ln == 0) { sh.red[w] = s; sh.red[8 + w] = q; }
  __syncthreads();
  float ts = 0.f, tq = 0.f;
#pragma unroll
  for (int k = 0; k < 8; ++k) { ts += sh.red[k]; tq += sh.red[8 + k]; }
  float mu = ts * (1.0f / D2);
  float rstd = rsqrtf(tq * (1.0f / D2) - mu * mu + EPS_F);
#pragma unroll
  for (int k = 0; k < 4; ++k) {
    int idx = tid * 4 + k;
    out[(size_t)t * D2 + idx] = (y[k] - mu) * rstd * g2[idx] + b2[idx];
  }
}

// ---- Coop mega: {build ∥ stream} -> sync -> {gather+GEMM+flush} -> sync -> final.
__global__ __launch_bounds__(512, 8) void mega_kernel(
    const float* __restrict__ x, const float* __restrict__ g1, const float* __restrict__ b1,
    const int* __restrict__ node_idx, const int* __restrict__ sidx,
    const float* __restrict__ g2, const float* __restrict__ b2,
    unsigned* __restrict__ W8w, float* __restrict__ Agg, float* __restrict__ out) {
  cg::grid_group grid = cg::this_grid();
  __shared__ SharedT sh;
  const int gtid = blockIdx.x * BLK_C + threadIdx.x;
  const int t = blockIdx.x >> 6, chunk = blockIdx.x & 63;

  // Build-W (first 98 blocks) overlaps every block's x-stream.
  if (gtid < COMP_LEN_C * MAX_LEN_C) {
    int c = gtid / MAX_LEN_C;
    int n = sidx[gtid];
    int byteoff = n * COMP_LEN_C + c;
    atomicAdd(&W8w[byteoff >> 2], 1u << (8 * (byteoff & 3)));
  }
  int nid4[4];
  phaseA_stream(sh, t, chunk, x, g1, b1, node_idx, nid4);
  grid.sync();                       // W built; vtile resident in LDS
  phaseB_gemmflush(sh, t, (const unsigned*)W8w, nid4, Agg);
  grid.sync();                       // Agg complete
  if (blockIdx.x < T_DIM) phaseC_final(sh, blockIdx.x, Agg, g2, b2, out);
}

// ---- Fallback (non-coop), identical math, dispatch-ordered.
__global__ void build_w8_kernel(const int* __restrict__ sidx, unsigned* __restrict__ W8w) {
  const int c  = blockIdx.x >> 2;
  const int jc = blockIdx.x & 3;
  const int j  = jc * 196 + threadIdx.x;
  if (j < MAX_LEN_C && threadIdx.x < 196) {
    int n = sidx[c * MAX_LEN_C + j];
    int byteoff = n * COMP_LEN_C + c;
    atomicAdd(&W8w[byteoff >> 2], 1u << (8 * (byteoff & 3)));
  }
}
__global__ __launch_bounds__(512, 8) void main_nc(
    const float* __restrict__ x, const float* __restrict__ g1, const float* __restrict__ b1,
    const int* __restrict__ node_idx, const unsigned* __restrict__ W32,
    float* __restrict__ Agg) {
  __shared__ SharedT sh;
  const int t = blockIdx.x >> 6, chunk = blockIdx.x & 63;
  int nid4[4];
  phaseA_stream(sh, t, chunk, x, g1, b1, node_idx, nid4);
  phaseB_gemmflush(sh, t, W32, nid4, Agg);
}
__global__ __launch_bounds__(512) void final_nc(
    const float* __restrict__ Agg, const float* __restrict__ g2,
    const float* __restrict__ b2, float* __restrict__ out) {
  __shared__ SharedT sh;
  phaseC_final(sh, blockIdx.x, Agg, g2, b2, out);
}

extern "C" void kernel_launch(void* const* d_in, const int* in_sizes, int n_in,
                              void* d_out, int out_size, void* d_ws, size_t ws_size,
                              hipStream_t stream) {
  const float* x     = (const float*)d_in[0];
  const float* ln1_g = (const float*)d_in[1];
  const float* ln1_b = (const float*)d_in[2];
  const float* ln2_g = (const float*)d_in[3];
  const float* ln2_b = (const float*)d_in[4];
  const int* node_idx = (const int*)d_in[5];
  const int* sidx     = (const int*)d_in[6];
  float* out = (float*)d_out;

  unsigned char* ws = (unsigned char*)d_ws;
  unsigned* W8w = (unsigned*)ws;
  float* Agg = (float*)(ws + AGG_OFF);

  hipMemsetAsync(ws, 0, ZERO_BYTES, stream);   // W8 + Agg (replay-safe)

  int maxActive = 0;
  hipError_t occ = hipOccupancyMaxActiveBlocksPerMultiprocessor(
      &maxActive, (const void*)mega_kernel, BLK_C, 0);
  bool coop = (occ == hipSuccess) && (maxActive >= 4);   // 1024 blocks / 256 CU

  if (coop) {
    void* args[] = {(void*)&x, (void*)&ln1_g, (void*)&ln1_b, (void*)&node_idx,
                    (void*)&sidx, (void*)&ln2_g, (void*)&ln2_b,
                    (void*)&W8w, (void*)&Agg, (void*)&out};
    hipError_t e = hipLaunchCooperativeKernel((void*)mega_kernel, dim3(GRID_C),
                                              dim3(BLK_C), args, 0, stream);
    if (e == hipSuccess) return;
  }

  build_w8_kernel<<<COMP_LEN_C * 4, 256, 0, stream>>>(sidx, W8w);
  main_nc<<<GRID_C, BLK_C, 0, stream>>>(x, ln1_g, ln1_b, node_idx,
                                        (const unsigned*)W8w, Agg);
  final_nc<<<T_DIM, 512, 0, stream>>>(Agg, ln2_g, ln2_b, out);
}